// Round 1
// baseline (571.269 us; speedup 1.0000x reference)
//
#include <hip/hip_runtime.h>

#define N_NODES 50000
#define N_EDGES 800000
#define F_IN    512
#define F_HID   64
#define F_OUT   16

// ---------------- degree / norm ----------------
__global__ void k_deg_init(float* __restrict__ deg) {
    int i = blockIdx.x * blockDim.x + threadIdx.x;
    if (i < N_NODES) deg[i] = 1.0f;  // self-loop contributes 1
}

__global__ void k_deg_accum(const int* __restrict__ dst, float* __restrict__ deg) {
    int e = blockIdx.x * blockDim.x + threadIdx.x;
    if (e < N_EDGES) atomicAdd(&deg[dst[e]], 1.0f);
}

__global__ void k_dinv(float* __restrict__ deg) {
    int i = blockIdx.x * blockDim.x + threadIdx.x;
    if (i < N_NODES) {
        float d = deg[i];
        deg[i] = d > 0.0f ? rsqrtf(d) : 0.0f;
    }
}

// ---------------- GEMM1: x[N,512] @ W1[512,64] -> h[N,64] ----------------
// 256 threads = 4 waves; wave w computes rows [row0+8w, row0+8w+8), col = lane.
// k tiled by 64, x tile staged in LDS (8 KB), W1 k-slice L1-resident.
__global__ __launch_bounds__(256) void k_gemm1(const float* __restrict__ x,
                                               const float* __restrict__ W,
                                               float* __restrict__ h) {
    __shared__ float xs[32][64];
    const int col = threadIdx.x & 63;
    const int wv  = threadIdx.x >> 6;   // 0..3
    const int row0 = blockIdx.x * 32;

    float acc[8];
#pragma unroll
    for (int m = 0; m < 8; ++m) acc[m] = 0.0f;

    for (int kt = 0; kt < F_IN; kt += 64) {
        __syncthreads();
        for (int idx = threadIdx.x; idx < 32 * 64; idx += 256) {
            int r = idx >> 6, kk = idx & 63;
            int row = row0 + r;
            xs[r][kk] = (row < N_NODES) ? x[(size_t)row * F_IN + kt + kk] : 0.0f;
        }
        __syncthreads();
#pragma unroll 8
        for (int kk = 0; kk < 64; ++kk) {
            float w = W[(size_t)(kt + kk) * F_HID + col];
#pragma unroll
            for (int m = 0; m < 8; ++m)
                acc[m] = fmaf(xs[wv * 8 + m][kk], w, acc[m]);
        }
    }
#pragma unroll
    for (int m = 0; m < 8; ++m) {
        int row = row0 + wv * 8 + m;
        if (row < N_NODES) h[(size_t)row * F_HID + col] = acc[m];
    }
}

// ---------------- edge scatter, F=64: one 64-lane group per edge ----------------
__global__ void k_agg64(const int* __restrict__ src, const int* __restrict__ dst,
                        const float* __restrict__ dinv, const float* __restrict__ h,
                        float* __restrict__ agg) {
    long long t = (long long)blockIdx.x * blockDim.x + threadIdx.x;
    int e = (int)(t >> 6);
    int j = (int)(t & 63);
    if (e < N_EDGES) {
        int s = src[e], d = dst[e];
        float w = dinv[s] * dinv[d];
        atomicAdd(&agg[(size_t)d * F_HID + j], h[(size_t)s * F_HID + j] * w);
    }
}

// self-loop + bias + relu, result (h1) written in place into agg
__global__ void k_post1(const float* __restrict__ h, const float* __restrict__ dinv,
                        const float* __restrict__ b1, float* __restrict__ agg) {
    int t = blockIdx.x * blockDim.x + threadIdx.x;
    if (t < N_NODES * F_HID) {
        int i = t >> 6, j = t & 63;
        float di = dinv[i];
        float v = agg[t] + h[t] * di * di + b1[j];
        agg[t] = fmaxf(v, 0.0f);
    }
}

// ---------------- GEMM2: h1[N,64] @ W2[64,16] -> h2[N,16] ----------------
__global__ void k_gemm2(const float* __restrict__ h1, const float* __restrict__ W,
                        float* __restrict__ h2) {
    int t = blockIdx.x * blockDim.x + threadIdx.x;
    if (t < N_NODES * F_OUT) {
        int i = t >> 4, j = t & 15;
        float acc = 0.0f;
#pragma unroll
        for (int k = 0; k < F_HID; ++k)
            acc = fmaf(h1[(size_t)i * F_HID + k], W[k * F_OUT + j], acc);
        h2[t] = acc;
    }
}

// ---------------- edge scatter, F=16, accumulate into d_out ----------------
__global__ void k_agg16(const int* __restrict__ src, const int* __restrict__ dst,
                        const float* __restrict__ dinv, const float* __restrict__ h2,
                        float* __restrict__ out) {
    long long t = (long long)blockIdx.x * blockDim.x + threadIdx.x;
    int e = (int)(t >> 4);
    int j = (int)(t & 15);
    if (e < N_EDGES) {
        int s = src[e], d = dst[e];
        float w = dinv[s] * dinv[d];
        atomicAdd(&out[(size_t)d * F_OUT + j], h2[(size_t)s * F_OUT + j] * w);
    }
}

__global__ void k_post2(const float* __restrict__ h2, const float* __restrict__ dinv,
                        const float* __restrict__ b2, float* __restrict__ out) {
    int t = blockIdx.x * blockDim.x + threadIdx.x;
    if (t < N_NODES * F_OUT) {
        int i = t >> 4, j = t & 15;
        float di = dinv[i];
        out[t] += h2[t] * di * di + b2[j];
    }
}

extern "C" void kernel_launch(void* const* d_in, const int* in_sizes, int n_in,
                              void* d_out, int out_size, void* d_ws, size_t ws_size,
                              hipStream_t stream) {
    const float* x  = (const float*)d_in[0];
    const int*   ei = (const int*)d_in[1];       // [2, E] int
    const float* W1 = (const float*)d_in[2];
    const float* b1 = (const float*)d_in[3];
    const float* W2 = (const float*)d_in[4];
    const float* b2 = (const float*)d_in[5];
    float* out = (float*)d_out;

    const int* src = ei;
    const int* dst = ei + N_EDGES;

    // workspace layout (floats)
    float* ws = (float*)d_ws;
    float* dinv = ws;                             // N (reused: deg -> dinv)
    float* h    = ws + 51200;                     // N*64
    float* agg1 = h + (size_t)N_NODES * F_HID;    // N*64 (becomes h1)
    float* h2   = agg1 + (size_t)N_NODES * F_HID; // N*16

    // zero the accumulators we scatter into
    hipMemsetAsync(agg1, 0, (size_t)N_NODES * F_HID * sizeof(float), stream);
    hipMemsetAsync(d_out, 0, (size_t)N_NODES * F_OUT * sizeof(float), stream);

    // degree / norm
    k_deg_init<<<(N_NODES + 255) / 256, 256, 0, stream>>>(dinv);
    k_deg_accum<<<(N_EDGES + 255) / 256, 256, 0, stream>>>(dst, dinv);
    k_dinv<<<(N_NODES + 255) / 256, 256, 0, stream>>>(dinv);

    // layer 1
    k_gemm1<<<(N_NODES + 31) / 32, 256, 0, stream>>>(x, W1, h);
    {
        long long threads = (long long)N_EDGES * 64;
        k_agg64<<<(int)((threads + 255) / 256), 256, 0, stream>>>(src, dst, dinv, h, agg1);
    }
    k_post1<<<(N_NODES * F_HID + 255) / 256, 256, 0, stream>>>(h, dinv, b1, agg1);

    // layer 2
    k_gemm2<<<(N_NODES * F_OUT + 255) / 256, 256, 0, stream>>>(agg1, W2, h2);
    {
        long long threads = (long long)N_EDGES * 16;
        k_agg16<<<(int)((threads + 255) / 256), 256, 0, stream>>>(src, dst, dinv, h2, out);
    }
    k_post2<<<(N_NODES * F_OUT + 255) / 256, 256, 0, stream>>>(h2, dinv, b2, out);
}

// Round 2
// 477.831 us; speedup vs baseline: 1.1955x; 1.1955x over previous
//
#include <hip/hip_runtime.h>

#define N_NODES 50000
#define N_EDGES 800000
#define F_IN    512
#define F_HID   64
#define F_OUT   16

#define SCAN_B  1024
#define SCAN_NB ((N_NODES + SCAN_B - 1) / SCAN_B)   // 49

// ---------------- CSR build ----------------
// count in-degree (excluding self loops) at dst
__global__ void k_count(const int* __restrict__ dst, int* __restrict__ count) {
    int e = blockIdx.x * blockDim.x + threadIdx.x;
    if (e < N_EDGES) atomicAdd(&count[dst[e]], 1);
}

// per-block exclusive scan of count -> offs (block-local), block totals -> bsum,
// fused dinv = rsqrt(count+1)
__global__ __launch_bounds__(SCAN_B) void k_scanA(const int* __restrict__ count,
                                                  int* __restrict__ offs,
                                                  int* __restrict__ bsum,
                                                  float* __restrict__ dinv) {
    __shared__ int s[SCAN_B];
    int t = threadIdx.x;
    int i = blockIdx.x * SCAN_B + t;
    int v = (i < N_NODES) ? count[i] : 0;
    s[t] = v;
    __syncthreads();
    for (int off = 1; off < SCAN_B; off <<= 1) {
        int u = (t >= off) ? s[t - off] : 0;
        __syncthreads();
        s[t] += u;
        __syncthreads();
    }
    if (i < N_NODES) {
        offs[i] = s[t] - v;                      // exclusive, block-local
        dinv[i] = rsqrtf((float)(v + 1));        // deg includes self-loop
    }
    if (t == SCAN_B - 1) bsum[blockIdx.x] = s[t];
}

// single-wave scan of block sums -> exclusive block offsets
__global__ void k_scanB(const int* __restrict__ bsum, int* __restrict__ boff) {
    int lane = threadIdx.x;   // 64 threads, 1 wave
    int v = (lane < SCAN_NB) ? bsum[lane] : 0;
    int orig = v;
    for (int d = 1; d < 64; d <<= 1) {
        int u = __shfl_up(v, d);
        if (lane >= d) v += u;
    }
    if (lane < SCAN_NB) boff[lane] = v - orig;
}

__global__ __launch_bounds__(SCAN_B) void k_scanC(int* __restrict__ offs,
                                                  const int* __restrict__ boff) {
    int i = blockIdx.x * SCAN_B + threadIdx.x;
    if (i < N_NODES) offs[i] += boff[blockIdx.x];
    if (i == 0) offs[N_NODES] = N_EDGES;
}

// scatter edge sources into dst-grouped slots (cursor aliases count, re-zeroed)
__global__ void k_fill(const int* __restrict__ src, const int* __restrict__ dst,
                       const int* __restrict__ offs, int* __restrict__ cursor,
                       int* __restrict__ src_sorted) {
    int e = blockIdx.x * blockDim.x + threadIdx.x;
    if (e < N_EDGES) {
        int d = dst[e];
        int pos = atomicAdd(&cursor[d], 1);
        src_sorted[offs[d] + pos] = src[e];
    }
}

// ---------------- GEMM1: x[N,512] @ W1[512,64] -> h[N,64] ----------------
__global__ __launch_bounds__(256) void k_gemm1(const float* __restrict__ x,
                                               const float* __restrict__ W,
                                               float* __restrict__ h) {
    __shared__ float xs[32][64];
    const int col = threadIdx.x & 63;
    const int wv  = threadIdx.x >> 6;   // 0..3
    const int row0 = blockIdx.x * 32;

    float acc[8];
#pragma unroll
    for (int m = 0; m < 8; ++m) acc[m] = 0.0f;

    for (int kt = 0; kt < F_IN; kt += 64) {
        __syncthreads();
        for (int idx = threadIdx.x; idx < 32 * 64; idx += 256) {
            int r = idx >> 6, kk = idx & 63;
            int row = row0 + r;
            xs[r][kk] = (row < N_NODES) ? x[(size_t)row * F_IN + kt + kk] : 0.0f;
        }
        __syncthreads();
#pragma unroll 8
        for (int kk = 0; kk < 64; ++kk) {
            float w = W[(size_t)(kt + kk) * F_HID + col];
#pragma unroll
            for (int m = 0; m < 8; ++m)
                acc[m] = fmaf(xs[wv * 8 + m][kk], w, acc[m]);
        }
    }
#pragma unroll
    for (int m = 0; m < 8; ++m) {
        int row = row0 + wv * 8 + m;
        if (row < N_NODES) h[(size_t)row * F_HID + col] = acc[m];
    }
}

// ---------------- CSR aggregation F=64, fused self-loop+bias+ReLU ----------------
// one 64-lane wave per node; lane = feature
__global__ __launch_bounds__(256) void k_agg64_csr(const int* __restrict__ offs,
                                                   const int* __restrict__ src_sorted,
                                                   const float* __restrict__ dinv,
                                                   const float* __restrict__ h,
                                                   const float* __restrict__ b1,
                                                   float* __restrict__ h1) {
    int node = blockIdx.x * 4 + (threadIdx.x >> 6);
    int j = threadIdx.x & 63;
    if (node >= N_NODES) return;
    float dn = dinv[node];
    float acc = h[(size_t)node * F_HID + j] * dn * dn;   // self loop
    int k0 = offs[node], k1 = offs[node + 1];
    for (int k = k0; k < k1; ++k) {
        int s = src_sorted[k];
        float w = dinv[s] * dn;
        acc = fmaf(h[(size_t)s * F_HID + j], w, acc);
    }
    h1[(size_t)node * F_HID + j] = fmaxf(acc + b1[j], 0.0f);
}

// ---------------- GEMM2: h1[N,64] @ W2[64,16] -> h2[N,16] ----------------
__global__ void k_gemm2(const float* __restrict__ h1, const float* __restrict__ W,
                        float* __restrict__ h2) {
    int t = blockIdx.x * blockDim.x + threadIdx.x;
    if (t < N_NODES * F_OUT) {
        int i = t >> 4, j = t & 15;
        float acc = 0.0f;
#pragma unroll
        for (int k = 0; k < F_HID; ++k)
            acc = fmaf(h1[(size_t)i * F_HID + k], W[k * F_OUT + j], acc);
        h2[t] = acc;
    }
}

// ---------------- CSR aggregation F=16, fused self-loop+bias ----------------
// one wave per node: lanes split into 4 edge-groups x 16 features
__global__ __launch_bounds__(256) void k_agg16_csr(const int* __restrict__ offs,
                                                   const int* __restrict__ src_sorted,
                                                   const float* __restrict__ dinv,
                                                   const float* __restrict__ h2,
                                                   const float* __restrict__ b2,
                                                   float* __restrict__ out) {
    int node = blockIdx.x * 4 + (threadIdx.x >> 6);
    int lane = threadIdx.x & 63;
    int eo = lane >> 4;          // 0..3
    int j  = lane & 15;
    if (node >= N_NODES) return;
    float dn = dinv[node];
    float acc = 0.0f;
    int k0 = offs[node], k1 = offs[node + 1];
    for (int k = k0 + eo; k < k1; k += 4) {
        int s = src_sorted[k];
        float w = dinv[s] * dn;
        acc = fmaf(h2[(size_t)s * F_OUT + j], w, acc);
    }
    acc += __shfl_xor(acc, 16);
    acc += __shfl_xor(acc, 32);
    if (eo == 0)
        out[(size_t)node * F_OUT + j] =
            acc + h2[(size_t)node * F_OUT + j] * dn * dn + b2[j];
}

extern "C" void kernel_launch(void* const* d_in, const int* in_sizes, int n_in,
                              void* d_out, int out_size, void* d_ws, size_t ws_size,
                              hipStream_t stream) {
    const float* x  = (const float*)d_in[0];
    const int*   ei = (const int*)d_in[1];
    const float* W1 = (const float*)d_in[2];
    const float* b1 = (const float*)d_in[3];
    const float* W2 = (const float*)d_in[4];
    const float* b2 = (const float*)d_in[5];
    float* out = (float*)d_out;

    const int* src = ei;
    const int* dst = ei + N_EDGES;

    // workspace layout (4-byte elems)
    int* wsi = (int*)d_ws;
    int* count      = wsi;                  // 50176 (also reused as fill cursor)
    int* offs       = count + 50176;        // 50304 (N+1 padded)
    int* bsum       = offs + 50304;         // 64
    int* boff       = bsum + 64;            // 64
    int* src_sorted = boff + 64;            // 800000
    float* dinv = (float*)(src_sorted + N_EDGES);        // 50176
    float* h    = dinv + 50176;                          // N*64
    float* h1   = h + (size_t)N_NODES * F_HID;           // N*64
    float* h2   = h;                                     // alias: h dead after agg64

    // ---- CSR build ----
    hipMemsetAsync(count, 0, N_NODES * sizeof(int), stream);
    k_count<<<(N_EDGES + 255) / 256, 256, 0, stream>>>(dst, count);
    k_scanA<<<SCAN_NB, SCAN_B, 0, stream>>>(count, offs, bsum, dinv);
    k_scanB<<<1, 64, 0, stream>>>(bsum, boff);
    k_scanC<<<SCAN_NB, SCAN_B, 0, stream>>>(offs, boff);
    hipMemsetAsync(count, 0, N_NODES * sizeof(int), stream);   // reuse as cursor
    k_fill<<<(N_EDGES + 255) / 256, 256, 0, stream>>>(src, dst, offs, count, src_sorted);

    // ---- layer 1 ----
    k_gemm1<<<(N_NODES + 31) / 32, 256, 0, stream>>>(x, W1, h);
    k_agg64_csr<<<(N_NODES + 3) / 4, 256, 0, stream>>>(offs, src_sorted, dinv, h, b1, h1);

    // ---- layer 2 ----
    k_gemm2<<<(N_NODES * F_OUT + 255) / 256, 256, 0, stream>>>(h1, W2, h2);
    k_agg16_csr<<<(N_NODES + 3) / 4, 256, 0, stream>>>(offs, src_sorted, dinv, h2, b2, out);
}

// Round 3
// 392.646 us; speedup vs baseline: 1.4549x; 1.2170x over previous
//
#include <hip/hip_runtime.h>

#define N_NODES 50000
#define N_EDGES 800000
#define F_IN    512
#define F_HID   64
#define F_OUT   16

#define SCAN_B  1024
#define SCAN_NB ((N_NODES + SCAN_B - 1) / SCAN_B)   // 49

typedef short bf16x8 __attribute__((ext_vector_type(8)));
typedef float f32x4  __attribute__((ext_vector_type(4)));

// ---------------- CSR build ----------------
__global__ void k_count(const int* __restrict__ dst, int* __restrict__ count) {
    int e = blockIdx.x * blockDim.x + threadIdx.x;
    if (e < N_EDGES) atomicAdd(&count[dst[e]], 1);
}

__global__ __launch_bounds__(SCAN_B) void k_scanA(const int* __restrict__ count,
                                                  int* __restrict__ offs,
                                                  int* __restrict__ bsum,
                                                  float* __restrict__ dinv) {
    __shared__ int s[SCAN_B];
    int t = threadIdx.x;
    int i = blockIdx.x * SCAN_B + t;
    int v = (i < N_NODES) ? count[i] : 0;
    s[t] = v;
    __syncthreads();
    for (int off = 1; off < SCAN_B; off <<= 1) {
        int u = (t >= off) ? s[t - off] : 0;
        __syncthreads();
        s[t] += u;
        __syncthreads();
    }
    if (i < N_NODES) {
        offs[i] = s[t] - v;
        dinv[i] = rsqrtf((float)(v + 1));
    }
    if (t == SCAN_B - 1) bsum[blockIdx.x] = s[t];
}

__global__ void k_scanB(const int* __restrict__ bsum, int* __restrict__ boff) {
    int lane = threadIdx.x;
    int v = (lane < SCAN_NB) ? bsum[lane] : 0;
    int orig = v;
    for (int d = 1; d < 64; d <<= 1) {
        int u = __shfl_up(v, d);
        if (lane >= d) v += u;
    }
    if (lane < SCAN_NB) boff[lane] = v - orig;
}

__global__ __launch_bounds__(SCAN_B) void k_scanC(int* __restrict__ offs,
                                                  const int* __restrict__ boff) {
    int i = blockIdx.x * SCAN_B + threadIdx.x;
    if (i < N_NODES) offs[i] += boff[blockIdx.x];
    if (i == 0) offs[N_NODES] = N_EDGES;
}

__global__ void k_fill(const int* __restrict__ src, const int* __restrict__ dst,
                       const int* __restrict__ offs, int* __restrict__ cursor,
                       int* __restrict__ src_sorted) {
    int e = blockIdx.x * blockDim.x + threadIdx.x;
    if (e < N_EDGES) {
        int d = dst[e];
        int pos = atomicAdd(&cursor[d], 1);
        src_sorted[offs[d] + pos] = src[e];
    }
}

// ---------------- W1 split-precision pack into MFMA B-operand layout ----------
// B-frag (16x16x32): lane = n + 16*q holds B[k = s*32 + q*8 + j][n], j=0..7
// layout: [(s*4 + t)*64 + lane]*8 + j   (t = col-tile of 16)
__global__ void k_prep_b(const float* __restrict__ W, short* __restrict__ bhi,
                         short* __restrict__ blo) {
    int tid = blockIdx.x * blockDim.x + threadIdx.x;   // 4096 total
    if (tid >= 16 * 4 * 64) return;
    int lane = tid & 63;
    int t = (tid >> 6) & 3;
    int s = tid >> 8;
    int n = t * 16 + (lane & 15);
    int q = lane >> 4;
    for (int j = 0; j < 8; ++j) {
        int k = s * 32 + q * 8 + j;
        float w = W[k * F_HID + n];
        unsigned u = __float_as_uint(w);
        float hif = __uint_as_float(u & 0xffff0000u);
        unsigned ul = __float_as_uint(w - hif);
        size_t idx = ((size_t)(s * 4 + t) * 64 + lane) * 8 + j;
        bhi[idx] = (short)(u >> 16);
        blo[idx] = (short)(ul >> 16);
    }
}

// ---------------- GEMM1 via bf16 MFMA, split-precision (hi+lo) ----------------
// wave handles 16 rows x 64 cols; A f32 loaded direct from global, split in-reg.
__global__ __launch_bounds__(256) void k_gemm1_mfma(const float* __restrict__ x,
                                                    const short* __restrict__ bhi,
                                                    const short* __restrict__ blo,
                                                    float* __restrict__ h) {
    const int wave = threadIdx.x >> 6;
    const int lane = threadIdx.x & 63;
    const int m = lane & 15, q = lane >> 4;
    const int r0 = (blockIdx.x * 4 + wave) * 16;
    int row = r0 + m;
    if (row >= N_NODES) row = N_NODES - 1;           // clamp loads; store guarded
    const float* xrow = x + (size_t)row * F_IN + q * 8;

    f32x4 acc[4] = {f32x4{0,0,0,0}, f32x4{0,0,0,0}, f32x4{0,0,0,0}, f32x4{0,0,0,0}};

    for (int s = 0; s < 16; ++s) {
        f32x4 a0 = *(const f32x4*)(xrow + s * 32);
        f32x4 a1 = *(const f32x4*)(xrow + s * 32 + 4);
        bf16x8 ahi, alo;
#pragma unroll
        for (int j = 0; j < 8; ++j) {
            float v = (j < 4) ? a0[j] : a1[j - 4];
            unsigned u = __float_as_uint(v);
            float hif = __uint_as_float(u & 0xffff0000u);
            unsigned ul = __float_as_uint(v - hif);
            ahi[j] = (short)(u >> 16);
            alo[j] = (short)(ul >> 16);
        }
#pragma unroll
        for (int t = 0; t < 4; ++t) {
            size_t bidx = ((size_t)(s * 4 + t) * 64 + lane) * 8;
            bf16x8 bh = *(const bf16x8*)(bhi + bidx);
            bf16x8 bl = *(const bf16x8*)(blo + bidx);
            acc[t] = __builtin_amdgcn_mfma_f32_16x16x32_bf16(ahi, bh, acc[t], 0, 0, 0);
            acc[t] = __builtin_amdgcn_mfma_f32_16x16x32_bf16(alo, bh, acc[t], 0, 0, 0);
            acc[t] = __builtin_amdgcn_mfma_f32_16x16x32_bf16(ahi, bl, acc[t], 0, 0, 0);
        }
    }
    // D layout: col = lane&15, row(within 16) = q*4 + r
#pragma unroll
    for (int t = 0; t < 4; ++t) {
#pragma unroll
        for (int r = 0; r < 4; ++r) {
            int rr = r0 + q * 4 + r;
            if (rr < N_NODES)
                h[(size_t)rr * F_HID + t * 16 + m] = acc[t][r];
        }
    }
}

// ---------------- CSR aggregation F=64, fused self-loop+bias+ReLU -------------
__global__ __launch_bounds__(256) void k_agg64_csr(const int* __restrict__ offs,
                                                   const int* __restrict__ src_sorted,
                                                   const float* __restrict__ dinv,
                                                   const float* __restrict__ h,
                                                   const float* __restrict__ b1,
                                                   float* __restrict__ h1) {
    int node = blockIdx.x * 4 + (threadIdx.x >> 6);
    int j = threadIdx.x & 63;
    if (node >= N_NODES) return;
    float dn = dinv[node];
    float acc = h[(size_t)node * F_HID + j] * dn * dn;
    int k0 = offs[node], k1 = offs[node + 1];
    for (int k = k0; k < k1; ++k) {
        int s = src_sorted[k];
        float w = dinv[s] * dn;
        acc = fmaf(h[(size_t)s * F_HID + j], w, acc);
    }
    h1[(size_t)node * F_HID + j] = fmaxf(acc + b1[j], 0.0f);
}

// ---------------- GEMM2: h1[N,64] @ W2[64,16] -> h2[N,16] ----------------
__global__ void k_gemm2(const float* __restrict__ h1, const float* __restrict__ W,
                        float* __restrict__ h2) {
    int t = blockIdx.x * blockDim.x + threadIdx.x;
    if (t < N_NODES * F_OUT) {
        int i = t >> 4, j = t & 15;
        float acc = 0.0f;
#pragma unroll
        for (int k = 0; k < F_HID; ++k)
            acc = fmaf(h1[(size_t)i * F_HID + k], W[k * F_OUT + j], acc);
        h2[t] = acc;
    }
}

// ---------------- CSR aggregation F=16, fused self-loop+bias ------------------
__global__ __launch_bounds__(256) void k_agg16_csr(const int* __restrict__ offs,
                                                   const int* __restrict__ src_sorted,
                                                   const float* __restrict__ dinv,
                                                   const float* __restrict__ h2,
                                                   const float* __restrict__ b2,
                                                   float* __restrict__ out) {
    int node = blockIdx.x * 4 + (threadIdx.x >> 6);
    int lane = threadIdx.x & 63;
    int eo = lane >> 4;
    int j  = lane & 15;
    if (node >= N_NODES) return;
    float dn = dinv[node];
    float acc = 0.0f;
    int k0 = offs[node], k1 = offs[node + 1];
    for (int k = k0 + eo; k < k1; k += 4) {
        int s = src_sorted[k];
        float w = dinv[s] * dn;
        acc = fmaf(h2[(size_t)s * F_OUT + j], w, acc);
    }
    acc += __shfl_xor(acc, 16);
    acc += __shfl_xor(acc, 32);
    if (eo == 0)
        out[(size_t)node * F_OUT + j] =
            acc + h2[(size_t)node * F_OUT + j] * dn * dn + b2[j];
}

extern "C" void kernel_launch(void* const* d_in, const int* in_sizes, int n_in,
                              void* d_out, int out_size, void* d_ws, size_t ws_size,
                              hipStream_t stream) {
    const float* x  = (const float*)d_in[0];
    const int*   ei = (const int*)d_in[1];
    const float* W1 = (const float*)d_in[2];
    const float* b1 = (const float*)d_in[3];
    const float* W2 = (const float*)d_in[4];
    const float* b2 = (const float*)d_in[5];
    float* out = (float*)d_out;

    const int* src = ei;
    const int* dst = ei + N_EDGES;

    // workspace layout (4-byte elems)
    int* wsi = (int*)d_ws;
    int* count      = wsi;                  // 50176 (reused as fill cursor)
    int* offs       = count + 50176;        // 50304
    int* bsum       = offs + 50304;         // 64
    int* boff       = bsum + 64;            // 64
    int* src_sorted = boff + 64;            // 800000
    float* dinv = (float*)(src_sorted + N_EDGES);        // 50176
    float* h    = dinv + 50176;                          // N*64
    float* h1   = h + (size_t)N_NODES * F_HID;           // N*64
    short* bhi  = (short*)(h1 + (size_t)N_NODES * F_HID); // 32768 bf16
    short* blo  = bhi + 32768;                            // 32768 bf16
    float* h2   = h;                                      // alias: h dead after agg64

    // ---- CSR build + W1 pack ----
    hipMemsetAsync(count, 0, N_NODES * sizeof(int), stream);
    k_prep_b<<<16, 256, 0, stream>>>(W1, bhi, blo);
    k_count<<<(N_EDGES + 255) / 256, 256, 0, stream>>>(dst, count);
    k_scanA<<<SCAN_NB, SCAN_B, 0, stream>>>(count, offs, bsum, dinv);
    k_scanB<<<1, 64, 0, stream>>>(bsum, boff);
    k_scanC<<<SCAN_NB, SCAN_B, 0, stream>>>(offs, boff);
    hipMemsetAsync(count, 0, N_NODES * sizeof(int), stream);
    k_fill<<<(N_EDGES + 255) / 256, 256, 0, stream>>>(src, dst, offs, count, src_sorted);

    // ---- layer 1 ----
    k_gemm1_mfma<<<(N_NODES + 63) / 64, 256, 0, stream>>>(x, bhi, blo, h);
    k_agg64_csr<<<(N_NODES + 3) / 4, 256, 0, stream>>>(offs, src_sorted, dinv, h, b1, h1);

    // ---- layer 2 ----
    k_gemm2<<<(N_NODES * F_OUT + 255) / 256, 256, 0, stream>>>(h1, W2, h2);
    k_agg16_csr<<<(N_NODES + 3) / 4, 256, 0, stream>>>(offs, src_sorted, dinv, h2, b2, out);
}

// Round 4
// 359.919 us; speedup vs baseline: 1.5872x; 1.0909x over previous
//
#include <hip/hip_runtime.h>

#define N_NODES 50000
#define N_EDGES 800000
#define F_IN    512
#define F_HID   64
#define F_OUT   16

#define SCAN_B  1024
#define SCAN_NB ((N_NODES + SCAN_B - 1) / SCAN_B)   // 49

typedef short bf16x8 __attribute__((ext_vector_type(8)));
typedef float f32x4  __attribute__((ext_vector_type(4)));

// ---------------- CSR build ----------------
__global__ void k_count(const int* __restrict__ dst, int* __restrict__ count) {
    int e = blockIdx.x * blockDim.x + threadIdx.x;
    if (e < N_EDGES) atomicAdd(&count[dst[e]], 1);
}

__global__ __launch_bounds__(SCAN_B) void k_scanA(const int* __restrict__ count,
                                                  int* __restrict__ offs,
                                                  int* __restrict__ bsum,
                                                  float* __restrict__ dinv) {
    __shared__ int s[SCAN_B];
    int t = threadIdx.x;
    int i = blockIdx.x * SCAN_B + t;
    int v = (i < N_NODES) ? count[i] : 0;
    s[t] = v;
    __syncthreads();
    for (int off = 1; off < SCAN_B; off <<= 1) {
        int u = (t >= off) ? s[t - off] : 0;
        __syncthreads();
        s[t] += u;
        __syncthreads();
    }
    if (i < N_NODES) {
        offs[i] = s[t] - v;
        dinv[i] = rsqrtf((float)(v + 1));
    }
    if (t == SCAN_B - 1) bsum[blockIdx.x] = s[t];
}

__global__ void k_scanB(const int* __restrict__ bsum, int* __restrict__ boff) {
    int lane = threadIdx.x;
    int v = (lane < SCAN_NB) ? bsum[lane] : 0;
    int orig = v;
    for (int d = 1; d < 64; d <<= 1) {
        int u = __shfl_up(v, d);
        if (lane >= d) v += u;
    }
    if (lane < SCAN_NB) boff[lane] = v - orig;
}

__global__ __launch_bounds__(SCAN_B) void k_scanC(int* __restrict__ offs,
                                                  const int* __restrict__ boff) {
    int i = blockIdx.x * SCAN_B + threadIdx.x;
    if (i < N_NODES) offs[i] += boff[blockIdx.x];
    if (i == 0) offs[N_NODES] = N_EDGES;
}

// scatter sources + precomputed edge weights into dst-grouped slots
__global__ void k_fill(const int* __restrict__ src, const int* __restrict__ dst,
                       const int* __restrict__ offs, int* __restrict__ cursor,
                       const float* __restrict__ dinv,
                       int* __restrict__ src_sorted, float* __restrict__ w_sorted) {
    int e = blockIdx.x * blockDim.x + threadIdx.x;
    if (e < N_EDGES) {
        int d = dst[e];
        int s = src[e];
        int pos = atomicAdd(&cursor[d], 1);
        int slot = offs[d] + pos;
        src_sorted[slot] = s;
        w_sorted[slot] = dinv[s] * dinv[d];
    }
}

// ---------------- W1 split-precision pack into MFMA B-operand layout ----------
__global__ void k_prep_b(const float* __restrict__ W, short* __restrict__ bhi,
                         short* __restrict__ blo) {
    int tid = blockIdx.x * blockDim.x + threadIdx.x;
    if (tid >= 16 * 4 * 64) return;
    int lane = tid & 63;
    int t = (tid >> 6) & 3;
    int s = tid >> 8;
    int n = t * 16 + (lane & 15);
    int q = lane >> 4;
    for (int j = 0; j < 8; ++j) {
        int k = s * 32 + q * 8 + j;
        float w = W[k * F_HID + n];
        unsigned u = __float_as_uint(w);
        float hif = __uint_as_float(u & 0xffff0000u);
        unsigned ul = __float_as_uint(w - hif);
        size_t idx = ((size_t)(s * 4 + t) * 64 + lane) * 8 + j;
        bhi[idx] = (short)(u >> 16);
        blo[idx] = (short)(ul >> 16);
    }
}

// ---------------- GEMM1 via bf16 MFMA, split-precision (hi+lo) ----------------
__global__ __launch_bounds__(256) void k_gemm1_mfma(const float* __restrict__ x,
                                                    const short* __restrict__ bhi,
                                                    const short* __restrict__ blo,
                                                    float* __restrict__ h) {
    const int wave = threadIdx.x >> 6;
    const int lane = threadIdx.x & 63;
    const int m = lane & 15, q = lane >> 4;
    const int r0 = (blockIdx.x * 4 + wave) * 16;
    int row = r0 + m;
    if (row >= N_NODES) row = N_NODES - 1;
    const float* xrow = x + (size_t)row * F_IN + q * 8;

    f32x4 acc[4] = {f32x4{0,0,0,0}, f32x4{0,0,0,0}, f32x4{0,0,0,0}, f32x4{0,0,0,0}};

    for (int s = 0; s < 16; ++s) {
        f32x4 a0 = *(const f32x4*)(xrow + s * 32);
        f32x4 a1 = *(const f32x4*)(xrow + s * 32 + 4);
        bf16x8 ahi, alo;
#pragma unroll
        for (int j = 0; j < 8; ++j) {
            float v = (j < 4) ? a0[j] : a1[j - 4];
            unsigned u = __float_as_uint(v);
            float hif = __uint_as_float(u & 0xffff0000u);
            unsigned ul = __float_as_uint(v - hif);
            ahi[j] = (short)(u >> 16);
            alo[j] = (short)(ul >> 16);
        }
#pragma unroll
        for (int t = 0; t < 4; ++t) {
            size_t bidx = ((size_t)(s * 4 + t) * 64 + lane) * 8;
            bf16x8 bh = *(const bf16x8*)(bhi + bidx);
            bf16x8 bl = *(const bf16x8*)(blo + bidx);
            acc[t] = __builtin_amdgcn_mfma_f32_16x16x32_bf16(ahi, bh, acc[t], 0, 0, 0);
            acc[t] = __builtin_amdgcn_mfma_f32_16x16x32_bf16(alo, bh, acc[t], 0, 0, 0);
            acc[t] = __builtin_amdgcn_mfma_f32_16x16x32_bf16(ahi, bl, acc[t], 0, 0, 0);
        }
    }
#pragma unroll
    for (int t = 0; t < 4; ++t) {
#pragma unroll
        for (int r = 0; r < 4; ++r) {
            int rr = r0 + q * 4 + r;
            if (rr < N_NODES)
                h[(size_t)rr * F_HID + t * 16 + m] = acc[t][r];
        }
    }
}

// ---------------- CSR aggregation F=64: unroll-4, precomputed weights ---------
__global__ __launch_bounds__(256) void k_agg64_csr(const int* __restrict__ offs,
                                                   const int* __restrict__ srcs,
                                                   const float* __restrict__ wgt,
                                                   const float* __restrict__ dinv,
                                                   const float* __restrict__ h,
                                                   const float* __restrict__ b1,
                                                   float* __restrict__ h1) {
    int node = blockIdx.x * 4 + (threadIdx.x >> 6);
    int j = threadIdx.x & 63;
    if (node >= N_NODES) return;
    float dn = dinv[node];
    float acc0 = h[(size_t)node * F_HID + j] * dn * dn;   // self loop
    float acc1 = 0.0f;
    int k0 = offs[node], k1 = offs[node + 1];
    int k = k0;
    for (; k + 4 <= k1; k += 4) {
        int s0 = srcs[k], s1 = srcs[k + 1], s2 = srcs[k + 2], s3 = srcs[k + 3];
        float w0 = wgt[k], w1 = wgt[k + 1], w2 = wgt[k + 2], w3 = wgt[k + 3];
        float v0 = h[(size_t)s0 * F_HID + j];
        float v1 = h[(size_t)s1 * F_HID + j];
        float v2 = h[(size_t)s2 * F_HID + j];
        float v3 = h[(size_t)s3 * F_HID + j];
        acc0 = fmaf(v0, w0, acc0);
        acc1 = fmaf(v1, w1, acc1);
        acc0 = fmaf(v2, w2, acc0);
        acc1 = fmaf(v3, w3, acc1);
    }
    for (; k < k1; ++k)
        acc0 = fmaf(h[(size_t)srcs[k] * F_HID + j], wgt[k], acc0);
    h1[(size_t)node * F_HID + j] = fmaxf(acc0 + acc1 + b1[j], 0.0f);
}

// ---------------- GEMM2: h1[N,64] @ W2[64,16] -> h2[N,16] ----------------
__global__ void k_gemm2(const float* __restrict__ h1, const float* __restrict__ W,
                        float* __restrict__ h2) {
    int t = blockIdx.x * blockDim.x + threadIdx.x;
    if (t < N_NODES * F_OUT) {
        int i = t >> 4, j = t & 15;
        float acc = 0.0f;
#pragma unroll
        for (int k = 0; k < F_HID; ++k)
            acc = fmaf(h1[(size_t)i * F_HID + k], W[k * F_OUT + j], acc);
        h2[t] = acc;
    }
}

// ---------------- CSR aggregation F=16: 4 edge-groups x 16 feats, unroll-2 ----
__global__ __launch_bounds__(256) void k_agg16_csr(const int* __restrict__ offs,
                                                   const int* __restrict__ srcs,
                                                   const float* __restrict__ wgt,
                                                   const float* __restrict__ dinv,
                                                   const float* __restrict__ h2,
                                                   const float* __restrict__ b2,
                                                   float* __restrict__ out) {
    int node = blockIdx.x * 4 + (threadIdx.x >> 6);
    int lane = threadIdx.x & 63;
    int eo = lane >> 4;
    int j  = lane & 15;
    if (node >= N_NODES) return;
    float dn = dinv[node];
    float acc0 = 0.0f, acc1 = 0.0f;
    int k0 = offs[node], k1 = offs[node + 1];
    int k = k0 + eo;
    for (; k + 4 < k1; k += 8) {
        int s0 = srcs[k], s1 = srcs[k + 4];
        float w0 = wgt[k], w1 = wgt[k + 4];
        float v0 = h2[(size_t)s0 * F_OUT + j];
        float v1 = h2[(size_t)s1 * F_OUT + j];
        acc0 = fmaf(v0, w0, acc0);
        acc1 = fmaf(v1, w1, acc1);
    }
    if (k < k1)
        acc0 = fmaf(h2[(size_t)srcs[k] * F_OUT + j], wgt[k], acc0);
    float acc = acc0 + acc1;
    acc += __shfl_xor(acc, 16);
    acc += __shfl_xor(acc, 32);
    if (eo == 0)
        out[(size_t)node * F_OUT + j] =
            acc + h2[(size_t)node * F_OUT + j] * dn * dn + b2[j];
}

extern "C" void kernel_launch(void* const* d_in, const int* in_sizes, int n_in,
                              void* d_out, int out_size, void* d_ws, size_t ws_size,
                              hipStream_t stream) {
    const float* x  = (const float*)d_in[0];
    const int*   ei = (const int*)d_in[1];
    const float* W1 = (const float*)d_in[2];
    const float* b1 = (const float*)d_in[3];
    const float* W2 = (const float*)d_in[4];
    const float* b2 = (const float*)d_in[5];
    float* out = (float*)d_out;

    const int* src = ei;
    const int* dst = ei + N_EDGES;

    // workspace layout (4-byte elems)
    int* wsi = (int*)d_ws;
    int* count      = wsi;                  // 50176 (reused as fill cursor)
    int* offs       = count + 50176;        // 50304
    int* bsum       = offs + 50304;         // 64
    int* boff       = bsum + 64;            // 64
    int* src_sorted = boff + 64;            // 800000
    float* w_sorted = (float*)(src_sorted + N_EDGES);    // 800000
    float* dinv = w_sorted + N_EDGES;                    // 50176
    float* h    = dinv + 50176;                          // N*64
    float* h1   = h + (size_t)N_NODES * F_HID;           // N*64
    short* bhi  = (short*)(h1 + (size_t)N_NODES * F_HID); // 32768 bf16
    short* blo  = bhi + 32768;                            // 32768 bf16
    float* h2   = h;                                      // alias: h dead after agg64

    // ---- CSR build + W1 pack ----
    hipMemsetAsync(count, 0, N_NODES * sizeof(int), stream);
    k_prep_b<<<16, 256, 0, stream>>>(W1, bhi, blo);
    k_count<<<(N_EDGES + 255) / 256, 256, 0, stream>>>(dst, count);
    k_scanA<<<SCAN_NB, SCAN_B, 0, stream>>>(count, offs, bsum, dinv);
    k_scanB<<<1, 64, 0, stream>>>(bsum, boff);
    k_scanC<<<SCAN_NB, SCAN_B, 0, stream>>>(offs, boff);
    hipMemsetAsync(count, 0, N_NODES * sizeof(int), stream);
    k_fill<<<(N_EDGES + 255) / 256, 256, 0, stream>>>(src, dst, offs, count, dinv,
                                                      src_sorted, w_sorted);

    // ---- layer 1 ----
    k_gemm1_mfma<<<(N_NODES + 63) / 64, 256, 0, stream>>>(x, bhi, blo, h);
    k_agg64_csr<<<(N_NODES + 3) / 4, 256, 0, stream>>>(offs, src_sorted, w_sorted,
                                                       dinv, h, b1, h1);

    // ---- layer 2 ----
    k_gemm2<<<(N_NODES * F_OUT + 255) / 256, 256, 0, stream>>>(h1, W2, h2);
    k_agg16_csr<<<(N_NODES + 3) / 4, 256, 0, stream>>>(offs, src_sorted, w_sorted,
                                                       dinv, h2, b2, out);
}

// Round 5
// 346.678 us; speedup vs baseline: 1.6478x; 1.0382x over previous
//
#include <hip/hip_runtime.h>

#define N_NODES 50000
#define N_EDGES 800000
#define F_IN    512
#define F_HID   64
#define F_OUT   16

#define SCAN_B  1024
#define SCAN_NB ((N_NODES + SCAN_B - 1) / SCAN_B)   // 49

typedef short bf16x8 __attribute__((ext_vector_type(8)));
typedef float f32x4  __attribute__((ext_vector_type(4)));

// ---------------- CSR build ----------------
__global__ void k_count(const int* __restrict__ dst, int* __restrict__ count) {
    int e = blockIdx.x * blockDim.x + threadIdx.x;
    if (e < N_EDGES) atomicAdd(&count[dst[e]], 1);
}

__global__ __launch_bounds__(SCAN_B) void k_scanA(const int* __restrict__ count,
                                                  int* __restrict__ offs,
                                                  int* __restrict__ bsum,
                                                  float* __restrict__ dinv) {
    __shared__ int s[SCAN_B];
    int t = threadIdx.x;
    int i = blockIdx.x * SCAN_B + t;
    int v = (i < N_NODES) ? count[i] : 0;
    s[t] = v;
    __syncthreads();
    for (int off = 1; off < SCAN_B; off <<= 1) {
        int u = (t >= off) ? s[t - off] : 0;
        __syncthreads();
        s[t] += u;
        __syncthreads();
    }
    if (i < N_NODES) {
        offs[i] = s[t] - v;
        dinv[i] = rsqrtf((float)(v + 1));
    }
    if (t == SCAN_B - 1) bsum[blockIdx.x] = s[t];
}

__global__ void k_scanB(const int* __restrict__ bsum, int* __restrict__ boff) {
    int lane = threadIdx.x;
    int v = (lane < SCAN_NB) ? bsum[lane] : 0;
    int orig = v;
    for (int d = 1; d < 64; d <<= 1) {
        int u = __shfl_up(v, d);
        if (lane >= d) v += u;
    }
    if (lane < SCAN_NB) boff[lane] = v - orig;
}

__global__ __launch_bounds__(SCAN_B) void k_scanC(int* __restrict__ offs,
                                                  const int* __restrict__ boff) {
    int i = blockIdx.x * SCAN_B + threadIdx.x;
    if (i < N_NODES) offs[i] += boff[blockIdx.x];
    if (i == 0) offs[N_NODES] = N_EDGES;
}

__global__ void k_fill(const int* __restrict__ src, const int* __restrict__ dst,
                       const int* __restrict__ offs, int* __restrict__ cursor,
                       const float* __restrict__ dinv,
                       int* __restrict__ src_sorted, float* __restrict__ w_sorted) {
    int e = blockIdx.x * blockDim.x + threadIdx.x;
    if (e < N_EDGES) {
        int d = dst[e];
        int s = src[e];
        int pos = atomicAdd(&cursor[d], 1);
        int slot = offs[d] + pos;
        src_sorted[slot] = s;
        w_sorted[slot] = dinv[s] * dinv[d];
    }
}

// ---------------- W1 split-precision pack into MFMA B-operand layout ----------
__global__ void k_prep_b(const float* __restrict__ W, short* __restrict__ bhi,
                         short* __restrict__ blo) {
    int tid = blockIdx.x * blockDim.x + threadIdx.x;
    if (tid >= 16 * 4 * 64) return;
    int lane = tid & 63;
    int t = (tid >> 6) & 3;
    int s = tid >> 8;
    int n = t * 16 + (lane & 15);
    int q = lane >> 4;
    for (int j = 0; j < 8; ++j) {
        int k = s * 32 + q * 8 + j;
        float w = W[k * F_HID + n];
        unsigned u = __float_as_uint(w);
        float hif = __uint_as_float(u & 0xffff0000u);
        unsigned ul = __float_as_uint(w - hif);
        size_t idx = ((size_t)(s * 4 + t) * 64 + lane) * 8 + j;
        bhi[idx] = (short)(u >> 16);
        blo[idx] = (short)(ul >> 16);
    }
}

// ---------------- GEMM1: K split across 4 waves, LDS reduce ----------------
// block = 16 rows; wave w handles K slice [128w, 128w+128)
__global__ __launch_bounds__(256) void k_gemm1_mfma(const float* __restrict__ x,
                                                    const short* __restrict__ bhi,
                                                    const short* __restrict__ blo,
                                                    float* __restrict__ h) {
    __shared__ float red[4][64][17];
    const int wave = threadIdx.x >> 6;
    const int lane = threadIdx.x & 63;
    const int m = lane & 15, q = lane >> 4;
    const int r0 = blockIdx.x * 16;           // 3125 * 16 = 50000 exactly
    const float* xrow = x + (size_t)(r0 + m) * F_IN + q * 8;

    f32x4 acc[4] = {f32x4{0,0,0,0}, f32x4{0,0,0,0}, f32x4{0,0,0,0}, f32x4{0,0,0,0}};

#pragma unroll
    for (int si = 0; si < 4; ++si) {
        const int s = wave * 4 + si;
        f32x4 a0 = *(const f32x4*)(xrow + s * 32);
        f32x4 a1 = *(const f32x4*)(xrow + s * 32 + 4);
        bf16x8 ahi, alo;
#pragma unroll
        for (int j = 0; j < 8; ++j) {
            float v = (j < 4) ? a0[j] : a1[j - 4];
            unsigned u = __float_as_uint(v);
            float hif = __uint_as_float(u & 0xffff0000u);
            unsigned ul = __float_as_uint(v - hif);
            ahi[j] = (short)(u >> 16);
            alo[j] = (short)(ul >> 16);
        }
#pragma unroll
        for (int t = 0; t < 4; ++t) {
            size_t bidx = ((size_t)(s * 4 + t) * 64 + lane) * 8;
            bf16x8 bh = *(const bf16x8*)(bhi + bidx);
            bf16x8 bl = *(const bf16x8*)(blo + bidx);
            acc[t] = __builtin_amdgcn_mfma_f32_16x16x32_bf16(ahi, bh, acc[t], 0, 0, 0);
            acc[t] = __builtin_amdgcn_mfma_f32_16x16x32_bf16(alo, bh, acc[t], 0, 0, 0);
            acc[t] = __builtin_amdgcn_mfma_f32_16x16x32_bf16(ahi, bl, acc[t], 0, 0, 0);
        }
    }
    // stash partials: D layout col = t*16 + m, row(within 16) = q*4 + r
#pragma unroll
    for (int t = 0; t < 4; ++t)
#pragma unroll
        for (int r = 0; r < 4; ++r)
            red[wave][lane][t * 4 + r] = acc[t][r];
    __syncthreads();
    // reduce across waves + coalesced store
    for (int f = threadIdx.x; f < 16 * 64; f += 256) {
        int row = f >> 6, col = f & 63;
        int ln  = (col & 15) + 16 * (row >> 2);
        int idx = (col >> 4) * 4 + (row & 3);
        float v = red[0][ln][idx] + red[1][ln][idx] + red[2][ln][idx] + red[3][ln][idx];
        h[(size_t)(r0 + row) * F_HID + col] = v;
    }
}

// ---------------- CSR aggregation F=64: unroll-4, precomputed weights ---------
__global__ __launch_bounds__(256) void k_agg64_csr(const int* __restrict__ offs,
                                                   const int* __restrict__ srcs,
                                                   const float* __restrict__ wgt,
                                                   const float* __restrict__ dinv,
                                                   const float* __restrict__ h,
                                                   const float* __restrict__ b1,
                                                   float* __restrict__ h1) {
    int node = blockIdx.x * 4 + (threadIdx.x >> 6);
    int j = threadIdx.x & 63;
    if (node >= N_NODES) return;
    float dn = dinv[node];
    float acc0 = h[(size_t)node * F_HID + j] * dn * dn;
    float acc1 = 0.0f;
    int k0 = offs[node], k1 = offs[node + 1];
    int k = k0;
    for (; k + 4 <= k1; k += 4) {
        int s0 = srcs[k], s1 = srcs[k + 1], s2 = srcs[k + 2], s3 = srcs[k + 3];
        float w0 = wgt[k], w1 = wgt[k + 1], w2 = wgt[k + 2], w3 = wgt[k + 3];
        float v0 = h[(size_t)s0 * F_HID + j];
        float v1 = h[(size_t)s1 * F_HID + j];
        float v2 = h[(size_t)s2 * F_HID + j];
        float v3 = h[(size_t)s3 * F_HID + j];
        acc0 = fmaf(v0, w0, acc0);
        acc1 = fmaf(v1, w1, acc1);
        acc0 = fmaf(v2, w2, acc0);
        acc1 = fmaf(v3, w3, acc1);
    }
    for (; k < k1; ++k)
        acc0 = fmaf(h[(size_t)srcs[k] * F_HID + j], wgt[k], acc0);
    h1[(size_t)node * F_HID + j] = fmaxf(acc0 + acc1 + b1[j], 0.0f);
}

// ---------------- GEMM2: h1[N,64] @ W2[64,16] -> h2[N,16] ----------------
__global__ void k_gemm2(const float* __restrict__ h1, const float* __restrict__ W,
                        float* __restrict__ h2) {
    int t = blockIdx.x * blockDim.x + threadIdx.x;
    if (t < N_NODES * F_OUT) {
        int i = t >> 4, j = t & 15;
        float acc = 0.0f;
#pragma unroll
        for (int k = 0; k < F_HID; ++k)
            acc = fmaf(h1[(size_t)i * F_HID + k], W[k * F_OUT + j], acc);
        h2[t] = acc;
    }
}

// ---------------- CSR aggregation F=16 ----------------
__global__ __launch_bounds__(256) void k_agg16_csr(const int* __restrict__ offs,
                                                   const int* __restrict__ srcs,
                                                   const float* __restrict__ wgt,
                                                   const float* __restrict__ dinv,
                                                   const float* __restrict__ h2,
                                                   const float* __restrict__ b2,
                                                   float* __restrict__ out) {
    int node = blockIdx.x * 4 + (threadIdx.x >> 6);
    int lane = threadIdx.x & 63;
    int eo = lane >> 4;
    int j  = lane & 15;
    if (node >= N_NODES) return;
    float dn = dinv[node];
    float acc0 = 0.0f, acc1 = 0.0f;
    int k0 = offs[node], k1 = offs[node + 1];
    int k = k0 + eo;
    for (; k + 4 < k1; k += 8) {
        int s0 = srcs[k], s1 = srcs[k + 4];
        float w0 = wgt[k], w1 = wgt[k + 4];
        float v0 = h2[(size_t)s0 * F_OUT + j];
        float v1 = h2[(size_t)s1 * F_OUT + j];
        acc0 = fmaf(v0, w0, acc0);
        acc1 = fmaf(v1, w1, acc1);
    }
    if (k < k1)
        acc0 = fmaf(h2[(size_t)srcs[k] * F_OUT + j], wgt[k], acc0);
    float acc = acc0 + acc1;
    acc += __shfl_xor(acc, 16);
    acc += __shfl_xor(acc, 32);
    if (eo == 0)
        out[(size_t)node * F_OUT + j] =
            acc + h2[(size_t)node * F_OUT + j] * dn * dn + b2[j];
}

extern "C" void kernel_launch(void* const* d_in, const int* in_sizes, int n_in,
                              void* d_out, int out_size, void* d_ws, size_t ws_size,
                              hipStream_t stream) {
    const float* x  = (const float*)d_in[0];
    const int*   ei = (const int*)d_in[1];
    const float* W1 = (const float*)d_in[2];
    const float* b1 = (const float*)d_in[3];
    const float* W2 = (const float*)d_in[4];
    const float* b2 = (const float*)d_in[5];
    float* out = (float*)d_out;

    const int* src = ei;
    const int* dst = ei + N_EDGES;

    int* wsi = (int*)d_ws;
    int* count      = wsi;                  // 50176 (reused as fill cursor)
    int* offs       = count + 50176;        // 50304
    int* bsum       = offs + 50304;         // 64
    int* boff       = bsum + 64;            // 64
    int* src_sorted = boff + 64;            // 800000
    float* w_sorted = (float*)(src_sorted + N_EDGES);    // 800000
    float* dinv = w_sorted + N_EDGES;                    // 50176
    float* h    = dinv + 50176;                          // N*64
    float* h1   = h + (size_t)N_NODES * F_HID;           // N*64
    short* bhi  = (short*)(h1 + (size_t)N_NODES * F_HID); // 32768 bf16
    short* blo  = bhi + 32768;                            // 32768 bf16
    float* h2   = h;                                      // alias: h dead after agg64

    // ---- CSR build + W1 pack ----
    hipMemsetAsync(count, 0, N_NODES * sizeof(int), stream);
    k_prep_b<<<16, 256, 0, stream>>>(W1, bhi, blo);
    k_count<<<(N_EDGES + 255) / 256, 256, 0, stream>>>(dst, count);
    k_scanA<<<SCAN_NB, SCAN_B, 0, stream>>>(count, offs, bsum, dinv);
    k_scanB<<<1, 64, 0, stream>>>(bsum, boff);
    k_scanC<<<SCAN_NB, SCAN_B, 0, stream>>>(offs, boff);
    hipMemsetAsync(count, 0, N_NODES * sizeof(int), stream);
    k_fill<<<(N_EDGES + 255) / 256, 256, 0, stream>>>(src, dst, offs, count, dinv,
                                                      src_sorted, w_sorted);

    // ---- layer 1 ----
    k_gemm1_mfma<<<N_NODES / 16, 256, 0, stream>>>(x, bhi, blo, h);
    k_agg64_csr<<<(N_NODES + 3) / 4, 256, 0, stream>>>(offs, src_sorted, w_sorted,
                                                       dinv, h, b1, h1);

    // ---- layer 2 ----
    k_gemm2<<<(N_NODES * F_OUT + 255) / 256, 256, 0, stream>>>(h1, W2, h2);
    k_agg16_csr<<<(N_NODES + 3) / 4, 256, 0, stream>>>(offs, src_sorted, w_sorted,
                                                       dinv, h2, b2, out);
}

// Round 6
// 334.746 us; speedup vs baseline: 1.7066x; 1.0356x over previous
//
#include <hip/hip_runtime.h>

#define N_NODES 50000
#define N_EDGES 800000
#define F_IN    512
#define F_HID   64
#define F_OUT   16
#define NT      (N_NODES / 16)      // 3125 row tiles
#define G1GRID  512

#define SCAN_B  1024
#define SCAN_NB ((N_NODES + SCAN_B - 1) / SCAN_B)   // 49

typedef short bf16x8 __attribute__((ext_vector_type(8)));
typedef float f32x4  __attribute__((ext_vector_type(4)));

// ---------------- CSR build ----------------
__global__ void k_count(const int* __restrict__ dst, int* __restrict__ count) {
    int e = blockIdx.x * blockDim.x + threadIdx.x;
    if (e < N_EDGES) atomicAdd(&count[dst[e]], 1);
}

__global__ __launch_bounds__(SCAN_B) void k_scanA(const int* __restrict__ count,
                                                  int* __restrict__ offs,
                                                  int* __restrict__ bsum,
                                                  float* __restrict__ dinv) {
    __shared__ int s[SCAN_B];
    int t = threadIdx.x;
    int i = blockIdx.x * SCAN_B + t;
    int v = (i < N_NODES) ? count[i] : 0;
    s[t] = v;
    __syncthreads();
    for (int off = 1; off < SCAN_B; off <<= 1) {
        int u = (t >= off) ? s[t - off] : 0;
        __syncthreads();
        s[t] += u;
        __syncthreads();
    }
    if (i < N_NODES) {
        offs[i] = s[t] - v;
        dinv[i] = rsqrtf((float)(v + 1));
    }
    if (t == SCAN_B - 1) bsum[blockIdx.x] = s[t];
}

__global__ void k_scanB(const int* __restrict__ bsum, int* __restrict__ boff) {
    int lane = threadIdx.x;
    int v = (lane < SCAN_NB) ? bsum[lane] : 0;
    int orig = v;
    for (int d = 1; d < 64; d <<= 1) {
        int u = __shfl_up(v, d);
        if (lane >= d) v += u;
    }
    if (lane < SCAN_NB) boff[lane] = v - orig;
}

__global__ __launch_bounds__(SCAN_B) void k_scanC(int* __restrict__ offs,
                                                  const int* __restrict__ boff) {
    int i = blockIdx.x * SCAN_B + threadIdx.x;
    if (i < N_NODES) offs[i] += boff[blockIdx.x];
    if (i == 0) offs[N_NODES] = N_EDGES;
}

__global__ void k_fill(const int* __restrict__ src, const int* __restrict__ dst,
                       const int* __restrict__ offs, int* __restrict__ cursor,
                       const float* __restrict__ dinv,
                       int* __restrict__ src_sorted, float* __restrict__ w_sorted) {
    int e = blockIdx.x * blockDim.x + threadIdx.x;
    if (e < N_EDGES) {
        int d = dst[e];
        int s = src[e];
        int pos = atomicAdd(&cursor[d], 1);
        int slot = offs[d] + pos;
        src_sorted[slot] = s;
        w_sorted[slot] = dinv[s] * dinv[d];
    }
}

// ---------------- W1 split-precision pack into MFMA B-operand layout ----------
__global__ void k_prep_b(const float* __restrict__ W, short* __restrict__ bhi,
                         short* __restrict__ blo) {
    int tid = blockIdx.x * blockDim.x + threadIdx.x;
    if (tid >= 16 * 4 * 64) return;
    int lane = tid & 63;
    int t = (tid >> 6) & 3;
    int s = tid >> 8;
    int n = t * 16 + (lane & 15);
    int q = lane >> 4;
    for (int j = 0; j < 8; ++j) {
        int k = s * 32 + q * 8 + j;
        float w = W[k * F_HID + n];
        unsigned u = __float_as_uint(w);
        float hif = __uint_as_float(u & 0xffff0000u);
        unsigned ul = __float_as_uint(w - hif);
        size_t idx = ((size_t)(s * 4 + t) * 64 + lane) * 8 + j;
        bhi[idx] = (short)(u >> 16);
        blo[idx] = (short)(ul >> 16);
    }
}

// ---------------- GEMM1: register-persistent B, grid-stride row tiles --------
// 512 threads = 8 waves; wave w owns K slice [64w, 64w+64); B frags live in
// registers for the whole kernel; block strides over 16-row tiles.
__global__ __launch_bounds__(512, 2) void k_gemm1_mfma(const float* __restrict__ x,
                                                       const short* __restrict__ bhi,
                                                       const short* __restrict__ blo,
                                                       float* __restrict__ h) {
    __shared__ float red[8][64][17];
    const int wave = threadIdx.x >> 6;
    const int lane = threadIdx.x & 63;
    const int m = lane & 15, q = lane >> 4;

    // load this wave's B fragments once (16 KB wave-wide, one-time)
    bf16x8 Bh[2][4], Bl[2][4];
#pragma unroll
    for (int si = 0; si < 2; ++si) {
        const int s = wave * 2 + si;
#pragma unroll
        for (int t = 0; t < 4; ++t) {
            size_t bidx = ((size_t)(s * 4 + t) * 64 + lane) * 8;
            Bh[si][t] = *(const bf16x8*)(bhi + bidx);
            Bl[si][t] = *(const bf16x8*)(blo + bidx);
        }
    }

    int tile = blockIdx.x;
    // prologue: load A for first tile
    f32x4 a0[2], a1[2];
    {
        const float* xr = x + (size_t)(tile * 16 + m) * F_IN + q * 8;
#pragma unroll
        for (int si = 0; si < 2; ++si) {
            const int s = wave * 2 + si;
            a0[si] = *(const f32x4*)(xr + s * 32);
            a1[si] = *(const f32x4*)(xr + s * 32 + 4);
        }
    }

    while (true) {
        const int next = tile + G1GRID;
        f32x4 n0[2], n1[2];
        if (next < NT) {
            const float* xr = x + (size_t)(next * 16 + m) * F_IN + q * 8;
#pragma unroll
            for (int si = 0; si < 2; ++si) {
                const int s = wave * 2 + si;
                n0[si] = *(const f32x4*)(xr + s * 32);
                n1[si] = *(const f32x4*)(xr + s * 32 + 4);
            }
        }

        f32x4 acc[4] = {f32x4{0,0,0,0}, f32x4{0,0,0,0}, f32x4{0,0,0,0}, f32x4{0,0,0,0}};
#pragma unroll
        for (int si = 0; si < 2; ++si) {
            bf16x8 ahi, alo;
#pragma unroll
            for (int j = 0; j < 8; ++j) {
                float v = (j < 4) ? a0[si][j] : a1[si][j - 4];
                unsigned u = __float_as_uint(v);
                float hif = __uint_as_float(u & 0xffff0000u);
                unsigned ul = __float_as_uint(v - hif);
                ahi[j] = (short)(u >> 16);
                alo[j] = (short)(ul >> 16);
            }
#pragma unroll
            for (int t = 0; t < 4; ++t) {
                acc[t] = __builtin_amdgcn_mfma_f32_16x16x32_bf16(ahi, Bh[si][t], acc[t], 0, 0, 0);
                acc[t] = __builtin_amdgcn_mfma_f32_16x16x32_bf16(alo, Bh[si][t], acc[t], 0, 0, 0);
                acc[t] = __builtin_amdgcn_mfma_f32_16x16x32_bf16(ahi, Bl[si][t], acc[t], 0, 0, 0);
            }
        }

        // stash partials: D layout col = t*16 + m, row(within 16) = q*4 + r
#pragma unroll
        for (int t = 0; t < 4; ++t)
#pragma unroll
            for (int r = 0; r < 4; ++r)
                red[wave][lane][t * 4 + r] = acc[t][r];
        __syncthreads();
        // reduce 8 partials + coalesced store (tile is 4 KB contiguous in h)
        const int r0 = tile * 16;
        for (int f = threadIdx.x; f < 16 * 64; f += 512) {
            int row = f >> 6, col = f & 63;
            int ln  = (col & 15) + 16 * (row >> 2);
            int idx = (col >> 4) * 4 + (row & 3);
            float v = red[0][ln][idx] + red[1][ln][idx] + red[2][ln][idx] + red[3][ln][idx]
                    + red[4][ln][idx] + red[5][ln][idx] + red[6][ln][idx] + red[7][ln][idx];
            h[(size_t)(r0 + row) * F_HID + col] = v;
        }
        if (next >= NT) break;
        __syncthreads();
#pragma unroll
        for (int si = 0; si < 2; ++si) { a0[si] = n0[si]; a1[si] = n1[si]; }
        tile = next;
    }
}

// ---------------- CSR aggregation F=64: unroll-4, precomputed weights ---------
__global__ __launch_bounds__(256) void k_agg64_csr(const int* __restrict__ offs,
                                                   const int* __restrict__ srcs,
                                                   const float* __restrict__ wgt,
                                                   const float* __restrict__ dinv,
                                                   const float* __restrict__ h,
                                                   const float* __restrict__ b1,
                                                   float* __restrict__ h1) {
    int node = blockIdx.x * 4 + (threadIdx.x >> 6);
    int j = threadIdx.x & 63;
    if (node >= N_NODES) return;
    float dn = dinv[node];
    float acc0 = h[(size_t)node * F_HID + j] * dn * dn;
    float acc1 = 0.0f;
    int k0 = offs[node], k1 = offs[node + 1];
    int k = k0;
    for (; k + 4 <= k1; k += 4) {
        int s0 = srcs[k], s1 = srcs[k + 1], s2 = srcs[k + 2], s3 = srcs[k + 3];
        float w0 = wgt[k], w1 = wgt[k + 1], w2 = wgt[k + 2], w3 = wgt[k + 3];
        float v0 = h[(size_t)s0 * F_HID + j];
        float v1 = h[(size_t)s1 * F_HID + j];
        float v2 = h[(size_t)s2 * F_HID + j];
        float v3 = h[(size_t)s3 * F_HID + j];
        acc0 = fmaf(v0, w0, acc0);
        acc1 = fmaf(v1, w1, acc1);
        acc0 = fmaf(v2, w2, acc0);
        acc1 = fmaf(v3, w3, acc1);
    }
    for (; k < k1; ++k)
        acc0 = fmaf(h[(size_t)srcs[k] * F_HID + j], wgt[k], acc0);
    h1[(size_t)node * F_HID + j] = fmaxf(acc0 + acc1 + b1[j], 0.0f);
}

// ---------------- GEMM2: h1[N,64] @ W2[64,16] -> h2[N,16] ----------------
__global__ void k_gemm2(const float* __restrict__ h1, const float* __restrict__ W,
                        float* __restrict__ h2) {
    int t = blockIdx.x * blockDim.x + threadIdx.x;
    if (t < N_NODES * F_OUT) {
        int i = t >> 4, j = t & 15;
        float acc = 0.0f;
#pragma unroll
        for (int k = 0; k < F_HID; ++k)
            acc = fmaf(h1[(size_t)i * F_HID + k], W[k * F_OUT + j], acc);
        h2[t] = acc;
    }
}

// ---------------- CSR aggregation F=16 ----------------
__global__ __launch_bounds__(256) void k_agg16_csr(const int* __restrict__ offs,
                                                   const int* __restrict__ srcs,
                                                   const float* __restrict__ wgt,
                                                   const float* __restrict__ dinv,
                                                   const float* __restrict__ h2,
                                                   const float* __restrict__ b2,
                                                   float* __restrict__ out) {
    int node = blockIdx.x * 4 + (threadIdx.x >> 6);
    int lane = threadIdx.x & 63;
    int eo = lane >> 4;
    int j  = lane & 15;
    if (node >= N_NODES) return;
    float dn = dinv[node];
    float acc0 = 0.0f, acc1 = 0.0f;
    int k0 = offs[node], k1 = offs[node + 1];
    int k = k0 + eo;
    for (; k + 4 < k1; k += 8) {
        int s0 = srcs[k], s1 = srcs[k + 4];
        float w0 = wgt[k], w1 = wgt[k + 4];
        float v0 = h2[(size_t)s0 * F_OUT + j];
        float v1 = h2[(size_t)s1 * F_OUT + j];
        acc0 = fmaf(v0, w0, acc0);
        acc1 = fmaf(v1, w1, acc1);
    }
    if (k < k1)
        acc0 = fmaf(h2[(size_t)srcs[k] * F_OUT + j], wgt[k], acc0);
    float acc = acc0 + acc1;
    acc += __shfl_xor(acc, 16);
    acc += __shfl_xor(acc, 32);
    if (eo == 0)
        out[(size_t)node * F_OUT + j] =
            acc + h2[(size_t)node * F_OUT + j] * dn * dn + b2[j];
}

extern "C" void kernel_launch(void* const* d_in, const int* in_sizes, int n_in,
                              void* d_out, int out_size, void* d_ws, size_t ws_size,
                              hipStream_t stream) {
    const float* x  = (const float*)d_in[0];
    const int*   ei = (const int*)d_in[1];
    const float* W1 = (const float*)d_in[2];
    const float* b1 = (const float*)d_in[3];
    const float* W2 = (const float*)d_in[4];
    const float* b2 = (const float*)d_in[5];
    float* out = (float*)d_out;

    const int* src = ei;
    const int* dst = ei + N_EDGES;

    int* wsi = (int*)d_ws;
    int* count      = wsi;                  // 50176 (reused as fill cursor)
    int* offs       = count + 50176;        // 50304
    int* bsum       = offs + 50304;         // 64
    int* boff       = bsum + 64;            // 64
    int* src_sorted = boff + 64;            // 800000
    float* w_sorted = (float*)(src_sorted + N_EDGES);    // 800000
    float* dinv = w_sorted + N_EDGES;                    // 50176
    float* h    = dinv + 50176;                          // N*64
    float* h1   = h + (size_t)N_NODES * F_HID;           // N*64
    short* bhi  = (short*)(h1 + (size_t)N_NODES * F_HID); // 32768 bf16
    short* blo  = bhi + 32768;                            // 32768 bf16
    float* h2   = h;                                      // alias: h dead after agg64

    // ---- CSR build + W1 pack ----
    hipMemsetAsync(count, 0, N_NODES * sizeof(int), stream);
    k_prep_b<<<16, 256, 0, stream>>>(W1, bhi, blo);
    k_count<<<(N_EDGES + 255) / 256, 256, 0, stream>>>(dst, count);
    k_scanA<<<SCAN_NB, SCAN_B, 0, stream>>>(count, offs, bsum, dinv);
    k_scanB<<<1, 64, 0, stream>>>(bsum, boff);
    k_scanC<<<SCAN_NB, SCAN_B, 0, stream>>>(offs, boff);
    hipMemsetAsync(count, 0, N_NODES * sizeof(int), stream);
    k_fill<<<(N_EDGES + 255) / 256, 256, 0, stream>>>(src, dst, offs, count, dinv,
                                                      src_sorted, w_sorted);

    // ---- layer 1 ----
    k_gemm1_mfma<<<G1GRID, 512, 0, stream>>>(x, bhi, blo, h);
    k_agg64_csr<<<(N_NODES + 3) / 4, 256, 0, stream>>>(offs, src_sorted, w_sorted,
                                                       dinv, h, b1, h1);

    // ---- layer 2 ----
    k_gemm2<<<(N_NODES * F_OUT + 255) / 256, 256, 0, stream>>>(h1, W2, h2);
    k_agg16_csr<<<(N_NODES + 3) / 4, 256, 0, stream>>>(offs, src_sorted, w_sorted,
                                                       dinv, h2, b2, out);
}

// Round 8
// 328.334 us; speedup vs baseline: 1.7399x; 1.0195x over previous
//
#include <hip/hip_runtime.h>

#define N_NODES 50000
#define N_EDGES 800000
#define F_IN    512
#define F_HID   64
#define F_OUT   16
#define NT      (N_NODES / 16)      // 3125 row tiles
#define G1GRID  512                 // gemm1 blocks
#define CNTB    256                 // histogram blocks

#define SCAN_B  1024
#define SCAN_NB ((N_NODES + SCAN_B - 1) / SCAN_B)   // 49

typedef short bf16x8 __attribute__((ext_vector_type(8)));
typedef float f32x4  __attribute__((ext_vector_type(4)));

__device__ __forceinline__ short bhi_of(float v) {
    return (short)(__float_as_uint(v) >> 16);
}
__device__ __forceinline__ short blo_of(float v) {
    float hif = __uint_as_float(__float_as_uint(v) & 0xffff0000u);
    return (short)(__float_as_uint(v - hif) >> 16);
}

// ---------------- mega: blocks [0,CNTB) count in-degrees; rest do GEMM1 ------
// GEMM1: 8 waves, wave w owns K slice [64w,64w+64); B frags built from W1 once,
// register-persistent; block grid-strides over 16-row tiles with A prefetch.
__global__ __launch_bounds__(512) void k_mega(const float* __restrict__ x,
                                              const float* __restrict__ W1,
                                              const int* __restrict__ dst,
                                              int* __restrict__ count,
                                              float* __restrict__ h) {
    if (blockIdx.x < CNTB) {
        // ---- histogram path ----
        for (int e = blockIdx.x * 512 + threadIdx.x; e < N_EDGES; e += CNTB * 512)
            atomicAdd(&count[dst[e]], 1);
        return;
    }
    // ---- gemm1 path ----
    __shared__ float red[8][64][17];
    const int gb   = blockIdx.x - CNTB;
    const int wave = threadIdx.x >> 6;
    const int lane = threadIdx.x & 63;
    const int m = lane & 15, q = lane >> 4;

    // build this wave's B fragments from W1 (once per block lifetime)
    bf16x8 Bh[2][4], Bl[2][4];
#pragma unroll
    for (int si = 0; si < 2; ++si) {
        const int s = wave * 2 + si;
#pragma unroll
        for (int t = 0; t < 4; ++t)
#pragma unroll
            for (int j = 0; j < 8; ++j) {
                float w = W1[(size_t)(s * 32 + q * 8 + j) * F_HID + t * 16 + m];
                Bh[si][t][j] = bhi_of(w);
                Bl[si][t][j] = blo_of(w);
            }
    }

    int tile = gb;
    f32x4 a0[2], a1[2];
    {
        const float* xr = x + (size_t)(tile * 16 + m) * F_IN + q * 8;
#pragma unroll
        for (int si = 0; si < 2; ++si) {
            const int s = wave * 2 + si;
            a0[si] = *(const f32x4*)(xr + s * 32);
            a1[si] = *(const f32x4*)(xr + s * 32 + 4);
        }
    }

    while (true) {
        const int next = tile + G1GRID;
        f32x4 n0[2], n1[2];
        if (next < NT) {
            const float* xr = x + (size_t)(next * 16 + m) * F_IN + q * 8;
#pragma unroll
            for (int si = 0; si < 2; ++si) {
                const int s = wave * 2 + si;
                n0[si] = *(const f32x4*)(xr + s * 32);
                n1[si] = *(const f32x4*)(xr + s * 32 + 4);
            }
        }

        f32x4 acc[4] = {f32x4{0,0,0,0}, f32x4{0,0,0,0}, f32x4{0,0,0,0}, f32x4{0,0,0,0}};
#pragma unroll
        for (int si = 0; si < 2; ++si) {
            bf16x8 ahi, alo;
#pragma unroll
            for (int j = 0; j < 8; ++j) {
                float v = (j < 4) ? a0[si][j] : a1[si][j - 4];
                ahi[j] = bhi_of(v);
                alo[j] = blo_of(v);
            }
#pragma unroll
            for (int t = 0; t < 4; ++t) {
                acc[t] = __builtin_amdgcn_mfma_f32_16x16x32_bf16(ahi, Bh[si][t], acc[t], 0, 0, 0);
                acc[t] = __builtin_amdgcn_mfma_f32_16x16x32_bf16(alo, Bh[si][t], acc[t], 0, 0, 0);
                acc[t] = __builtin_amdgcn_mfma_f32_16x16x32_bf16(ahi, Bl[si][t], acc[t], 0, 0, 0);
            }
        }

#pragma unroll
        for (int t = 0; t < 4; ++t)
#pragma unroll
            for (int r = 0; r < 4; ++r)
                red[wave][lane][t * 4 + r] = acc[t][r];
        __syncthreads();
        const int r0 = tile * 16;
        for (int f = threadIdx.x; f < 16 * 64; f += 512) {
            int row = f >> 6, col = f & 63;
            int ln  = (col & 15) + 16 * (row >> 2);
            int idx = (col >> 4) * 4 + (row & 3);
            float v = red[0][ln][idx] + red[1][ln][idx] + red[2][ln][idx] + red[3][ln][idx]
                    + red[4][ln][idx] + red[5][ln][idx] + red[6][ln][idx] + red[7][ln][idx];
            h[(size_t)(r0 + row) * F_HID + col] = v;
        }
        if (next >= NT) break;
        __syncthreads();
#pragma unroll
        for (int si = 0; si < 2; ++si) { a0[si] = n0[si]; a1[si] = n1[si]; }
        tile = next;
    }
}

// ---------------- scanA: block-local exclusive scan + dinv --------------------
__global__ __launch_bounds__(SCAN_B) void k_scanA(const int* __restrict__ count,
                                                  int* __restrict__ offs,
                                                  int* __restrict__ bsum,
                                                  float* __restrict__ dinv) {
    __shared__ int s[SCAN_B];
    int t = threadIdx.x;
    int i = blockIdx.x * SCAN_B + t;
    int v = (i < N_NODES) ? count[i] : 0;
    s[t] = v;
    __syncthreads();
    for (int off = 1; off < SCAN_B; off <<= 1) {
        int u = (t >= off) ? s[t - off] : 0;
        __syncthreads();
        s[t] += u;
        __syncthreads();
    }
    if (i < N_NODES) {
        offs[i] = s[t] - v;
        dinv[i] = rsqrtf((float)(v + 1));
    }
    if (t == SCAN_B - 1) bsum[blockIdx.x] = s[t];
}

// ---------------- scanBC: per-block redundant reduce of block sums ------------
__global__ __launch_bounds__(SCAN_B) void k_scanBC(int* __restrict__ offs,
                                                   const int* __restrict__ bsum) {
    __shared__ int base;
    if (threadIdx.x < 64) {
        int v = ((int)threadIdx.x < (int)blockIdx.x) ? bsum[threadIdx.x] : 0;
        for (int d = 1; d < 64; d <<= 1) v += __shfl_xor(v, d);
        if (threadIdx.x == 0) base = v;
    }
    __syncthreads();
    int i = blockIdx.x * SCAN_B + threadIdx.x;
    if (i < N_NODES) offs[i] += base;
    if (i == 0) offs[N_NODES] = N_EDGES;
}

// ---------------- fill: atomicSub on degree array claims slots ----------------
__global__ void k_fill(const int* __restrict__ src, const int* __restrict__ dst,
                       const int* __restrict__ offs, int* __restrict__ count,
                       const float* __restrict__ dinv,
                       int* __restrict__ src_sorted, float* __restrict__ w_sorted) {
    int e = blockIdx.x * blockDim.x + threadIdx.x;
    if (e < N_EDGES) {
        int d = dst[e];
        int s = src[e];
        int pos = atomicSub(&count[d], 1) - 1;
        int slot = offs[d] + pos;
        src_sorted[slot] = s;
        w_sorted[slot] = dinv[s] * dinv[d];
    }
}

// ---------------- CSR aggregation F=64: unroll-8, 4 acc chains ----------------
__global__ __launch_bounds__(256) void k_agg64_csr(const int* __restrict__ offs,
                                                   const int* __restrict__ srcs,
                                                   const float* __restrict__ wgt,
                                                   const float* __restrict__ dinv,
                                                   const float* __restrict__ h,
                                                   const float* __restrict__ b1,
                                                   float* __restrict__ h1) {
    int node = blockIdx.x * 4 + (threadIdx.x >> 6);
    int j = threadIdx.x & 63;
    if (node >= N_NODES) return;
    float dn = dinv[node];
    float acc0 = h[(size_t)node * F_HID + j] * dn * dn;
    float acc1 = 0.0f, acc2 = 0.0f, acc3 = 0.0f;
    int k0 = offs[node], k1 = offs[node + 1];
    int k = k0;
    for (; k + 8 <= k1; k += 8) {
        int s0 = srcs[k],     s1 = srcs[k + 1], s2 = srcs[k + 2], s3 = srcs[k + 3];
        int s4 = srcs[k + 4], s5 = srcs[k + 5], s6 = srcs[k + 6], s7 = srcs[k + 7];
        float w0 = wgt[k],     w1 = wgt[k + 1], w2 = wgt[k + 2], w3 = wgt[k + 3];
        float w4 = wgt[k + 4], w5 = wgt[k + 5], w6 = wgt[k + 6], w7 = wgt[k + 7];
        float v0 = h[(size_t)s0 * F_HID + j];
        float v1 = h[(size_t)s1 * F_HID + j];
        float v2 = h[(size_t)s2 * F_HID + j];
        float v3 = h[(size_t)s3 * F_HID + j];
        float v4 = h[(size_t)s4 * F_HID + j];
        float v5 = h[(size_t)s5 * F_HID + j];
        float v6 = h[(size_t)s6 * F_HID + j];
        float v7 = h[(size_t)s7 * F_HID + j];
        acc0 = fmaf(v0, w0, acc0);
        acc1 = fmaf(v1, w1, acc1);
        acc2 = fmaf(v2, w2, acc2);
        acc3 = fmaf(v3, w3, acc3);
        acc0 = fmaf(v4, w4, acc0);
        acc1 = fmaf(v5, w5, acc1);
        acc2 = fmaf(v6, w6, acc2);
        acc3 = fmaf(v7, w7, acc3);
    }
    for (; k < k1; ++k)
        acc0 = fmaf(h[(size_t)srcs[k] * F_HID + j], wgt[k], acc0);
    h1[(size_t)node * F_HID + j] = fmaxf((acc0 + acc1) + (acc2 + acc3) + b1[j], 0.0f);
}

// ---------------- GEMM2: h1[N,64] @ W2[64,16] -> h2[N,16] ----------------
__global__ void k_gemm2(const float* __restrict__ h1, const float* __restrict__ W,
                        float* __restrict__ h2) {
    int t = blockIdx.x * blockDim.x + threadIdx.x;
    if (t < N_NODES * F_OUT) {
        int i = t >> 4, j = t & 15;
        float acc = 0.0f;
#pragma unroll
        for (int k = 0; k < F_HID; ++k)
            acc = fmaf(h1[(size_t)i * F_HID + k], W[k * F_OUT + j], acc);
        h2[t] = acc;
    }
}

// ---------------- CSR aggregation F=16: 4 groups x 16 feats, unroll-4 ---------
__global__ __launch_bounds__(256) void k_agg16_csr(const int* __restrict__ offs,
                                                   const int* __restrict__ srcs,
                                                   const float* __restrict__ wgt,
                                                   const float* __restrict__ dinv,
                                                   const float* __restrict__ h2,
                                                   const float* __restrict__ b2,
                                                   float* __restrict__ out) {
    int node = blockIdx.x * 4 + (threadIdx.x >> 6);
    int lane = threadIdx.x & 63;
    int eo = lane >> 4;
    int j  = lane & 15;
    if (node >= N_NODES) return;
    float dn = dinv[node];
    float acc0 = 0.0f, acc1 = 0.0f, acc2 = 0.0f, acc3 = 0.0f;
    int k0 = offs[node], k1 = offs[node + 1];
    int k = k0 + eo;
    for (; k + 12 < k1; k += 16) {
        int s0 = srcs[k], s1 = srcs[k + 4], s2 = srcs[k + 8], s3 = srcs[k + 12];
        float w0 = wgt[k], w1 = wgt[k + 4], w2 = wgt[k + 8], w3 = wgt[k + 12];
        float v0 = h2[(size_t)s0 * F_OUT + j];
        float v1 = h2[(size_t)s1 * F_OUT + j];
        float v2 = h2[(size_t)s2 * F_OUT + j];
        float v3 = h2[(size_t)s3 * F_OUT + j];
        acc0 = fmaf(v0, w0, acc0);
        acc1 = fmaf(v1, w1, acc1);
        acc2 = fmaf(v2, w2, acc2);
        acc3 = fmaf(v3, w3, acc3);
    }
    for (; k < k1; k += 4)
        acc0 = fmaf(h2[(size_t)srcs[k] * F_OUT + j], wgt[k], acc0);
    float acc = (acc0 + acc1) + (acc2 + acc3);
    acc += __shfl_xor(acc, 16);
    acc += __shfl_xor(acc, 32);
    if (eo == 0)
        out[(size_t)node * F_OUT + j] =
            acc + h2[(size_t)node * F_OUT + j] * dn * dn + b2[j];
}

extern "C" void kernel_launch(void* const* d_in, const int* in_sizes, int n_in,
                              void* d_out, int out_size, void* d_ws, size_t ws_size,
                              hipStream_t stream) {
    const float* x  = (const float*)d_in[0];
    const int*   ei = (const int*)d_in[1];
    const float* W1 = (const float*)d_in[2];
    const float* b1 = (const float*)d_in[3];
    const float* W2 = (const float*)d_in[4];
    const float* b2 = (const float*)d_in[5];
    float* out = (float*)d_out;

    const int* src = ei;
    const int* dst = ei + N_EDGES;

    int* wsi = (int*)d_ws;
    int* count      = wsi;                  // 50176 (consumed to 0 by k_fill)
    int* offs       = count + 50176;        // 50304
    int* bsum       = offs + 50304;         // 64
    int* src_sorted = bsum + 64;            // 800000
    float* w_sorted = (float*)(src_sorted + N_EDGES);    // 800000
    float* dinv = w_sorted + N_EDGES;                    // 50176
    float* h    = dinv + 50176;                          // N*64
    float* h1   = h + (size_t)N_NODES * F_HID;           // N*64
    float* h2   = h;                                     // alias: h dead after agg64

    (void)hipMemsetAsync(count, 0, N_NODES * sizeof(int), stream);

    // gemm1 + degree histogram in one launch
    k_mega<<<CNTB + G1GRID, 512, 0, stream>>>(x, W1, dst, count, h);

    k_scanA<<<SCAN_NB, SCAN_B, 0, stream>>>(count, offs, bsum, dinv);
    k_scanBC<<<SCAN_NB, SCAN_B, 0, stream>>>(offs, bsum);
    k_fill<<<(N_EDGES + 255) / 256, 256, 0, stream>>>(src, dst, offs, count, dinv,
                                                      src_sorted, w_sorted);

    k_agg64_csr<<<(N_NODES + 3) / 4, 256, 0, stream>>>(offs, src_sorted, w_sorted,
                                                       dinv, h, b1, h1);
    k_gemm2<<<(N_NODES * F_OUT + 255) / 256, 256, 0, stream>>>(h1, W2, h2);
    k_agg16_csr<<<(N_NODES + 3) / 4, 256, 0, stream>>>(offs, src_sorted, w_sorted,
                                                       dinv, h2, b2, out);
}